// Round 9
// baseline (363.076 us; speedup 1.0000x reference)
//
#include <hip/hip_runtime.h>
#include <math.h>

#define BB 32
#define LL 2048
#define EE 512
#define HH 512

typedef __bf16 bf16_t;
typedef bf16_t bf16x8 __attribute__((ext_vector_type(8)));
typedef float f32x4 __attribute__((ext_vector_type(4)));
typedef unsigned short u16x8 __attribute__((ext_vector_type(8)));

#define MFMA __builtin_amdgcn_mfma_f32_16x16x32_bf16

__device__ __forceinline__ unsigned short f2bf(float f) {
  unsigned int u = __builtin_bit_cast(unsigned int, f);
  unsigned int r = (u + 0x7FFFu + ((u >> 16) & 1u)) >> 16;  // RNE
  return (unsigned short)r;
}
__device__ __forceinline__ float bf2f(unsigned short s) {
  unsigned int u = ((unsigned int)s) << 16;
  return __builtin_bit_cast(float, u);
}
__device__ __forceinline__ bf16x8 ld_frag(const unsigned short* p) {
  u16x8 raw = *(const u16x8*)p;
  return __builtin_bit_cast(bf16x8, raw);
}
__device__ __forceinline__ float tanh_fast(float x) {
  x = fminf(fmaxf(x, -15.f), 15.f);
  float e2 = __expf(2.f * x);
  return (e2 - 1.f) / (e2 + 1.f);
}

// encA/hS: 64x512 bf16 tiles, stride 512 (no pad) with T2 XOR swizzle: the row's
// low 3 bits are XORed into the 16B-slot bits of the column -> b128 column-slice
// reads spread across bank groups (replaces R7's +8-ushort pad, saves 8KB LDS).
__device__ __forceinline__ int swz(int row, int col) {
  return row * 512 + (col ^ ((row & 7) << 3));
}

// sub-slab staging: 32 weight rows x 32 k per step, 2 frags/lane, global->reg->LDS.
__device__ __forceinline__ void w_issue2(const unsigned short* __restrict__ Wt,
                                         int rbase, int k0, int lane, u16x8 t[2]) {
  const unsigned short* g = Wt + (size_t)(rbase + (lane >> 2)) * 512 + k0 + (lane & 3) * 8;
  t[0] = *(const u16x8*)(g);
  t[1] = *(const u16x8*)(g + 16 * 512);
}
__device__ __forceinline__ void w_write2(unsigned short* buf, int lane, const u16x8 t[2]) {
  unsigned short* d = buf + (lane >> 2) * 32 + (lane & 3) * 8;
  *(u16x8*)(d) = t[0];
  *(u16x8*)(d + 16 * 32) = t[1];
}

// One GEMM1 k-window (64 enc rows = TWO paired items): write sub-slab t01, prefetch
// its window+2 replacement, 8 MFMA; same for t23. Per-wave in-order LDS makes the
// single 2KB buffer's read->overwrite safe. Each slab frag read feeds 4 MFMAs
// (vs 2 in R7) -> slab LDS traffic per item HALVED.
#define G1_WIN(S01, S23, W, PF) do {                                            \
    const int k0_ = (((W) + phase) & 15) * 32;                                  \
    const bf16x8 b0_ = ld_frag(&encA[swz(l15,      k0_ + quad * 8)]);           \
    const bf16x8 b1_ = ld_frag(&encA[swz(16 + l15, k0_ + quad * 8)]);           \
    const bf16x8 b2_ = ld_frag(&encA[swz(32 + l15, k0_ + quad * 8)]);           \
    const bf16x8 b3_ = ld_frag(&encA[swz(48 + l15, k0_ + quad * 8)]);           \
    w_write2(slab, lane, S01);                                                  \
    if (PF) w_issue2(WhT, wbase, (((W) + 2 + phase) & 15) * 32, lane, S01);     \
    {                                                                           \
      const bf16x8 af0_ = ld_frag(&slab[l15 * 32 + quad * 8]);                  \
      const bf16x8 af1_ = ld_frag(&slab[(16 + l15) * 32 + quad * 8]);           \
      acc[0][0] = MFMA(af0_, b0_, acc[0][0], 0, 0, 0);                          \
      acc[0][1] = MFMA(af0_, b1_, acc[0][1], 0, 0, 0);                          \
      acc[0][2] = MFMA(af0_, b2_, acc[0][2], 0, 0, 0);                          \
      acc[0][3] = MFMA(af0_, b3_, acc[0][3], 0, 0, 0);                          \
      acc[1][0] = MFMA(af1_, b0_, acc[1][0], 0, 0, 0);                          \
      acc[1][1] = MFMA(af1_, b1_, acc[1][1], 0, 0, 0);                          \
      acc[1][2] = MFMA(af1_, b2_, acc[1][2], 0, 0, 0);                          \
      acc[1][3] = MFMA(af1_, b3_, acc[1][3], 0, 0, 0);                          \
    }                                                                           \
    w_write2(slab, lane, S23);                                                  \
    if (PF) w_issue2(WhT, wbase + 32, (((W) + 2 + phase) & 15) * 32, lane, S23);\
    {                                                                           \
      const bf16x8 af2_ = ld_frag(&slab[l15 * 32 + quad * 8]);                  \
      const bf16x8 af3_ = ld_frag(&slab[(16 + l15) * 32 + quad * 8]);           \
      acc[2][0] = MFMA(af2_, b0_, acc[2][0], 0, 0, 0);                          \
      acc[2][1] = MFMA(af2_, b1_, acc[2][1], 0, 0, 0);                          \
      acc[2][2] = MFMA(af2_, b2_, acc[2][2], 0, 0, 0);                          \
      acc[2][3] = MFMA(af2_, b3_, acc[2][3], 0, 0, 0);                          \
      acc[3][0] = MFMA(af3_, b0_, acc[3][0], 0, 0, 0);                          \
      acc[3][1] = MFMA(af3_, b1_, acc[3][1], 0, 0, 0);                          \
      acc[3][2] = MFMA(af3_, b2_, acc[3][2], 0, 0, 0);                          \
      acc[3][3] = MFMA(af3_, b3_, acc[3][3], 0, 0, 0);                          \
    }                                                                           \
  } while (0)

#define G2_WIN(S01, S23, W, PF) do {                                            \
    const int k0_ = (((W) + phase) & 15) * 32;                                  \
    const bf16x8 a0_ = ld_frag(&hS[swz(l15,      k0_ + quad * 8)]);             \
    const bf16x8 a1_ = ld_frag(&hS[swz(16 + l15, k0_ + quad * 8)]);             \
    const bf16x8 a2_ = ld_frag(&hS[swz(32 + l15, k0_ + quad * 8)]);             \
    const bf16x8 a3_ = ld_frag(&hS[swz(48 + l15, k0_ + quad * 8)]);             \
    w_write2(slab, lane, S01);                                                  \
    if (PF) w_issue2(WcT, wbase, (((W) + 2 + phase) & 15) * 32, lane, S01);     \
    {                                                                           \
      const bf16x8 cf0_ = ld_frag(&slab[l15 * 32 + quad * 8]);                  \
      const bf16x8 cf1_ = ld_frag(&slab[(16 + l15) * 32 + quad * 8]);           \
      acc[0][0] = MFMA(a0_, cf0_, acc[0][0], 0, 0, 0);                          \
      acc[1][0] = MFMA(a1_, cf0_, acc[1][0], 0, 0, 0);                          \
      acc[2][0] = MFMA(a2_, cf0_, acc[2][0], 0, 0, 0);                          \
      acc[3][0] = MFMA(a3_, cf0_, acc[3][0], 0, 0, 0);                          \
      acc[0][1] = MFMA(a0_, cf1_, acc[0][1], 0, 0, 0);                          \
      acc[1][1] = MFMA(a1_, cf1_, acc[1][1], 0, 0, 0);                          \
      acc[2][1] = MFMA(a2_, cf1_, acc[2][1], 0, 0, 0);                          \
      acc[3][1] = MFMA(a3_, cf1_, acc[3][1], 0, 0, 0);                          \
    }                                                                           \
    w_write2(slab, lane, S23);                                                  \
    if (PF) w_issue2(WcT, wbase + 32, (((W) + 2 + phase) & 15) * 32, lane, S23);\
    {                                                                           \
      const bf16x8 cf2_ = ld_frag(&slab[l15 * 32 + quad * 8]);                  \
      const bf16x8 cf3_ = ld_frag(&slab[(16 + l15) * 32 + quad * 8]);           \
      acc[0][2] = MFMA(a0_, cf2_, acc[0][2], 0, 0, 0);                          \
      acc[1][2] = MFMA(a1_, cf2_, acc[1][2], 0, 0, 0);                          \
      acc[2][2] = MFMA(a2_, cf2_, acc[2][2], 0, 0, 0);                          \
      acc[3][2] = MFMA(a3_, cf2_, acc[3][2], 0, 0, 0);                          \
      acc[0][3] = MFMA(a0_, cf3_, acc[0][3], 0, 0, 0);                          \
      acc[1][3] = MFMA(a1_, cf3_, acc[1][3], 0, 0, 0);                          \
      acc[2][3] = MFMA(a2_, cf3_, acc[2][3], 0, 0, 0);                          \
      acc[3][3] = MFMA(a3_, cf3_, acc[3][3], 0, 0, 0);                          \
    }                                                                           \
  } while (0)

// ---------------- prep: transpose + fp32->bf16 convert of Wh, Wc; init work queue ----------------
__global__ __launch_bounds__(256) void prep_w(
    const float* __restrict__ Wh, const float* __restrict__ Wc,
    unsigned short* __restrict__ WhT, unsigned short* __restrict__ WcT,
    int* __restrict__ q)
{
  if (blockIdx.x == 0 && blockIdx.y == 0 && threadIdx.x == 0) *q = 0;
  const float* src = blockIdx.y ? Wc : Wh;
  unsigned short* dst = blockIdx.y ? WcT : WhT;
  const int tr = (blockIdx.x >> 3) * 64;
  const int tc = (blockIdx.x & 7) * 64;
  const int tid = threadIdx.x;
  __shared__ float tile[64][65];
  for (int i = tid; i < 64 * 16; i += 256) {
    const int r = i >> 4, c4 = (i & 15) << 2;
    const float4 v = *(const float4*)(src + (size_t)(tr + r) * 512 + tc + c4);
    tile[r][c4 + 0] = v.x; tile[r][c4 + 1] = v.y;
    tile[r][c4 + 2] = v.z; tile[r][c4 + 3] = v.w;
  }
  __syncthreads();
  for (int i = tid; i < 64 * 16; i += 256) {
    const int r = i >> 4, c4 = (i & 15) << 2;
    ushort4 pk;
    pk.x = f2bf(tile[c4 + 0][r]); pk.y = f2bf(tile[c4 + 1][r]);
    pk.z = f2bf(tile[c4 + 2][r]); pk.w = f2bf(tile[c4 + 3][r]);
    *(ushort4*)(dst + (size_t)(tc + r) * 512 + tr + c4) = pk;
  }
}

__device__ __forceinline__ int pop_valid(int* q, const int* __restrict__ lens,
                                         int nitems, int Lc) {
  int it;
  for (;;) {
    it = atomicAdd(q, 1);
    if (it >= nitems || lens[it & 31] > (it >> 5) * Lc) return it;
  }
}

// ---------------- main: R7 structure + ITEM PAIRING (two items share every weight pass) ----------------
// R8 proved 8 waves/CU is the hard operating point (AGPRs push unified regs >128;
// <=128 spills). So amortize instead: two single-pass items (Lc=32) are fused into
// one 64-row joint pass -> slab LDS traffic, L2 weight stream, and barrier count
// all HALVE per item. Slab = 2KB/wave single buffer staged as two 32-row sub-slabs
// with distance-2 register prefetch; encA/hS lose their pad to an XOR swizzle.
__global__ __launch_bounds__(512, 2) void attn_main(
    const float* __restrict__ enc, const int* __restrict__ lens,
    const unsigned short* __restrict__ WhT, const float* __restrict__ bh,
    const unsigned short* __restrict__ WcT,
    float* __restrict__ pm, float* __restrict__ ps, float* __restrict__ po,
    int* __restrict__ q, int C, int Lc)
{
  const int tid  = threadIdx.x;
  const int wave = tid >> 6;       // 0..7
  const int lane = tid & 63;
  const int quad = lane >> 4;
  const int l15  = lane & 15;
  const int wbase = wave * 64;     // wave's 64-wide h-slab (GEMM1) / e-slab (GEMM2)

  __shared__ __align__(16) unsigned short ebuf[2][64 * 512];  // 2 x 64KB (enc/h ping-pong)
  __shared__ __align__(16) unsigned short wslabS[8][32 * 32]; // 16KB (2KB/wave sub-slab)
  __shared__ __align__(16) float bhS[512];
  __shared__ int itemS[2];

  unsigned short* slab = wslabS[wave];
  bhS[tid] = bh[tid];
  const int nitems = 32 * C;

  // ---- prologue: pop first valid PAIR ----
  if (tid == 0) {
    itemS[0] = pop_valid(q, lens, nitems, Lc);
    itemS[1] = pop_valid(q, lens, nitems, Lc);
  }
  __syncthreads();
  int it0 = itemS[0], it1 = itemS[1];
  int pp = 0;

  ushort4 eP0[8], eP1[8];  // next pair's enc tiles, pre-converted to bf16 (16 regs each)
  {
    if (it0 < nitems) {
      const float* src = enc + ((size_t)(it0 & 31) * LL + (size_t)(it0 >> 5) * Lc) * EE;
#pragma unroll
      for (int k = 0; k < 8; k++) {
        const int i = tid + k * 512;
        const float4 v = *(const float4*)(src + (size_t)(i >> 7) * EE + ((i & 127) << 2));
        eP0[k].x = f2bf(v.x); eP0[k].y = f2bf(v.y); eP0[k].z = f2bf(v.z); eP0[k].w = f2bf(v.w);
      }
    }
    if (it1 < nitems) {
      const float* src = enc + ((size_t)(it1 & 31) * LL + (size_t)(it1 >> 5) * Lc) * EE;
#pragma unroll
      for (int k = 0; k < 8; k++) {
        const int i = tid + k * 512;
        const float4 v = *(const float4*)(src + (size_t)(i >> 7) * EE + ((i & 127) << 2));
        eP1[k].x = f2bf(v.x); eP1[k].y = f2bf(v.y); eP1[k].z = f2bf(v.z); eP1[k].w = f2bf(v.w);
      }
    }
  }

#pragma unroll 1
  for (;;) {
    if (it0 >= nitems) break;
    const int b0i = it0 & 31, c0i = it0 >> 5;
    const int l00 = c0i * Lc;
    const int nv0 = min(lens[b0i] - l00, Lc);    // >= 1 (pop skips invalid)
    int b1i = 0, c1i = 0, l01 = 0, nv1 = 0;
    if (it1 < nitems) { b1i = it1 & 31; c1i = it1 >> 5; l01 = c1i * Lc; nv1 = min(lens[b1i] - l01, Lc); }
    const int nvmax = nv0 > nv1 ? nv0 : nv1;
    const int phase = (it0 + wave) & 15;         // k-window de-phasing
    unsigned short* encA = ebuf[pp];
    unsigned short* hS   = ebuf[pp ^ 1];

    float stM[2][4], stS[2][4], stO[2][4];
#pragma unroll
    for (int h = 0; h < 2; h++)
#pragma unroll
      for (int et = 0; et < 4; et++) { stM[h][et] = -1e30f; stS[h][et] = 0.f; stO[h][et] = 0.f; }

    int nx0 = nitems, nx1 = nitems;

#pragma unroll 1
    for (int r0 = 0; r0 < nvmax; r0 += 32) {
      const bool lastPass = (r0 + 32 >= nvmax);

      // ---- stage: pass 0 writes PRE-CONVERTED prefetch regs; later passes sync ----
      if (r0 == 0) {
#pragma unroll
        for (int k = 0; k < 8; k++) {
          const int i = tid + k * 512;
          *(ushort4*)&encA[swz(i >> 7, (i & 127) << 2)] = eP0[k];
        }
        if (it1 < nitems) {
#pragma unroll
          for (int k = 0; k < 8; k++) {
            const int i = tid + k * 512;
            *(ushort4*)&encA[swz(32 + (i >> 7), (i & 127) << 2)] = eP1[k];
          }
        }
      } else {
        if (r0 < nv0) {
          const float* encRow = enc + ((size_t)b0i * LL + l00 + r0) * EE;
          for (int i = tid; i < 32 * 128; i += 512) {
            const int m = i >> 7, c4 = (i & 127) << 2;
            const float4 v = *(const float4*)(encRow + (size_t)m * EE + c4);
            ushort4 pk;
            pk.x = f2bf(v.x); pk.y = f2bf(v.y); pk.z = f2bf(v.z); pk.w = f2bf(v.w);
            *(ushort4*)&encA[swz(m, c4)] = pk;
          }
        }
        if (r0 < nv1) {
          const float* encRow = enc + ((size_t)b1i * LL + l01 + r0) * EE;
          for (int i = tid; i < 32 * 128; i += 512) {
            const int m = i >> 7, c4 = (i & 127) << 2;
            const float4 v = *(const float4*)(encRow + (size_t)m * EE + c4);
            ushort4 pk;
            pk.x = f2bf(v.x); pk.y = f2bf(v.y); pk.z = f2bf(v.z); pk.w = f2bf(v.w);
            *(ushort4*)&encA[swz(32 + m, c4)] = pk;
          }
        }
      }
      // pop next pair while others stage; published by the barrier below
      if (lastPass && tid == 0) {
        itemS[0] = pop_valid(q, lens, nitems, Lc);
        itemS[1] = pop_valid(q, lens, nitems, Lc);
      }
      __syncthreads();

      f32x4 acc[4][4];

      // ================= GEMM1: hT[64 x 64rows] per wave, acc[t][mt] =================
#pragma unroll
      for (int i = 0; i < 4; i++)
#pragma unroll
        for (int j = 0; j < 4; j++) acc[i][j] = (f32x4){0.f, 0.f, 0.f, 0.f};
      {
        u16x8 sA01[2], sA23[2], sB01[2], sB23[2];
        w_issue2(WhT, wbase,      ((0 + phase) & 15) * 32, lane, sA01);
        w_issue2(WhT, wbase + 32, ((0 + phase) & 15) * 32, lane, sA23);
        w_issue2(WhT, wbase,      ((1 + phase) & 15) * 32, lane, sB01);
        w_issue2(WhT, wbase + 32, ((1 + phase) & 15) * 32, lane, sB23);
#pragma unroll 1
        for (int kk = 0; kk < 16; kk += 2) {
          G1_WIN(sA01, sA23, kk + 0, kk + 2 < 16);
          G1_WIN(sB01, sB23, kk + 1, kk + 3 < 16);
        }
      }

      // ---- bias + tanh, pack -> hS (swizzled) ----
#pragma unroll
      for (int t = 0; t < 4; t++) {
        const f32x4 bv = *(const f32x4*)&bhS[wbase + t * 16 + quad * 4];
#pragma unroll
        for (int mt = 0; mt < 4; mt++) {
          ushort4 pk;
          pk.x = f2bf(tanh_fast(acc[t][mt][0] + bv[0]));
          pk.y = f2bf(tanh_fast(acc[t][mt][1] + bv[1]));
          pk.z = f2bf(tanh_fast(acc[t][mt][2] + bv[2]));
          pk.w = f2bf(tanh_fast(acc[t][mt][3] + bv[3]));
          *(ushort4*)&hS[swz(mt * 16 + l15, wbase + t * 16 + quad * 4)] = pk;
        }
      }
      __syncthreads();

      // ================= GEMM2: logits[64rows x 64e] per wave, acc[mt][et] =================
#pragma unroll
      for (int i = 0; i < 4; i++)
#pragma unroll
        for (int j = 0; j < 4; j++) acc[i][j] = (f32x4){0.f, 0.f, 0.f, 0.f};
      {
        u16x8 sA01[2], sA23[2], sB01[2], sB23[2];
        w_issue2(WcT, wbase,      ((0 + phase) & 15) * 32, lane, sA01);
        w_issue2(WcT, wbase + 32, ((0 + phase) & 15) * 32, lane, sA23);
        w_issue2(WcT, wbase,      ((1 + phase) & 15) * 32, lane, sB01);
        w_issue2(WcT, wbase + 32, ((1 + phase) & 15) * 32, lane, sB23);
#pragma unroll 1
        for (int kk = 0; kk < 16; kk += 2) {
          G2_WIN(sA01, sA23, kk + 0, kk + 2 < 16);
          G2_WIN(sB01, sB23, kk + 1, kk + 3 < 16);
        }
      }

      // ---- issue NEXT pair's enc loads (f32 in flight across softmax; cvt at tail) ----
      float4 tf0[8], tf1[8];
      if (lastPass) {
        nx0 = itemS[0]; nx1 = itemS[1];
        if (nx0 < nitems) {
          const float* src = enc + ((size_t)(nx0 & 31) * LL + (size_t)(nx0 >> 5) * Lc) * EE;
#pragma unroll
          for (int k = 0; k < 8; k++) {
            const int i = tid + k * 512;
            tf0[k] = *(const float4*)(src + (size_t)(i >> 7) * EE + ((i & 127) << 2));
          }
        }
        if (nx1 < nitems) {
          const float* src = enc + ((size_t)(nx1 & 31) * LL + (size_t)(nx1 >> 5) * Lc) * EE;
#pragma unroll
          for (int k = 0; k < 8; k++) {
            const int i = tid + k * 512;
            tf1[k] = *(const float4*)(src + (size_t)(i >> 7) * EE + ((i & 127) << 2));
          }
        }
      }

      // ---- masked online softmax, one independent state per item half ----
#pragma unroll
      for (int H = 0; H < 2; H++) {
        const int nvH = H ? nv1 : nv0;
#pragma unroll
        for (int et = 0; et < 4; et++) {
          const int e = wbase + et * 16 + l15;
          float lm = -1e30f;
#pragma unroll
          for (int mi = 0; mi < 2; mi++) {
            const int mt = H * 2 + mi;
#pragma unroll
            for (int r = 0; r < 4; r++) {
              const float vv = (r0 + mi * 16 + quad * 4 + r) < nvH ? acc[mt][et][r] : -1e30f;
              lm = fmaxf(lm, vv);
            }
          }
          lm = fmaxf(lm, __shfl_xor(lm, 16));
          lm = fmaxf(lm, __shfl_xor(lm, 32));
          float ls = 0.f, lo = 0.f;
#pragma unroll
          for (int mi = 0; mi < 2; mi++) {
            const int mt = H * 2 + mi;
#pragma unroll
            for (int r = 0; r < 4; r++) {
              const float vv = (r0 + mi * 16 + quad * 4 + r) < nvH ? acc[mt][et][r] : -1e30f;
              const float pexp = __expf(vv - lm);
              const float ev = bf2f(encA[swz(mt * 16 + quad * 4 + r, e)]);
              ls += pexp;
              lo += pexp * ev;
            }
          }
          ls += __shfl_xor(ls, 16); ls += __shfl_xor(ls, 32);
          lo += __shfl_xor(lo, 16); lo += __shfl_xor(lo, 32);
          const float Mn = fmaxf(stM[H][et], lm);
          const float sc = __expf(stM[H][et] - Mn);
          const float st = __expf(lm - Mn);
          stS[H][et] = stS[H][et] * sc + ls * st;
          stO[H][et] = stO[H][et] * sc + lo * st;
          stM[H][et] = Mn;
        }
      }

      // ---- convert prefetched f32 -> packed bf16 regs (max distance from issue) ----
      if (lastPass) {
        if (nx0 < nitems) {
#pragma unroll
          for (int k = 0; k < 8; k++) {
            eP0[k].x = f2bf(tf0[k].x); eP0[k].y = f2bf(tf0[k].y);
            eP0[k].z = f2bf(tf0[k].z); eP0[k].w = f2bf(tf0[k].w);
          }
        }
        if (nx1 < nitems) {
#pragma unroll
          for (int k = 0; k < 8; k++) {
            eP1[k].x = f2bf(tf1[k].x); eP1[k].y = f2bf(tf1[k].y);
            eP1[k].z = f2bf(tf1[k].z); eP1[k].w = f2bf(tf1[k].w);
          }
        }
      }
      __syncthreads();   // end of pass: all reads of encA/hS complete
    }

    if (quad == 0) {
      const size_t base0 = ((size_t)b0i * C + c0i) * EE;
#pragma unroll
      for (int et = 0; et < 4; et++) {
        const int e = wbase + et * 16 + l15;
        pm[base0 + e] = stM[0][et];
        ps[base0 + e] = stS[0][et];
        po[base0 + e] = stO[0][et];
      }
      if (it1 < nitems) {
        const size_t base1 = ((size_t)b1i * C + c1i) * EE;
#pragma unroll
        for (int et = 0; et < 4; et++) {
          const int e = wbase + et * 16 + l15;
          pm[base1 + e] = stM[1][et];
          ps[base1 + e] = stS[1][et];
          po[base1 + e] = stO[1][et];
        }
      }
    }

    it0 = nx0; it1 = nx1; pp ^= 1;
  }
}

// ---------------- combine over chunks (parallelized: 8 e-slabs x 4 c-groups) ----------------
__global__ __launch_bounds__(256) void attn_combine(
    const float* __restrict__ pm, const float* __restrict__ ps,
    const float* __restrict__ po, const int* __restrict__ lens,
    float* __restrict__ out, int C, int Lc)
{
  const int b  = blockIdx.y;
  const int e  = blockIdx.x * 64 + (threadIdx.x & 63);
  const int g  = threadIdx.x >> 6;  // c-group 0..3
  const int n  = lens[b];
  const int cmax = min(C, (n + Lc - 1) / Lc);

  float M = -1e30f, S = 0.f, O = 0.f;
  for (int c = g; c < cmax; c += 4) {
    const size_t base = ((size_t)b * C + c) * EE;
    const float m = pm[base + e];
    const float s = ps[base + e];
    const float o = po[base + e];
    const float Mn  = fmaxf(M, m);
    const float sc0 = __expf(M - Mn);
    const float sc1 = __expf(m - Mn);
    S = S * sc0 + s * sc1;
    O = O * sc0 + o * sc1;
    M = Mn;
  }

  __shared__ float sM[4][64], sS[4][64], sO[4][64];
  sM[g][threadIdx.x & 63] = M;
  sS[g][threadIdx.x & 63] = S;
  sO[g][threadIdx.x & 63] = O;
  __syncthreads();

  if (g == 0) {
    const int le = threadIdx.x & 63;
    float Mt = sM[0][le], St = sS[0][le], Ot = sO[0][le];
#pragma unroll
    for (int gg = 1; gg < 4; gg++) {
      const float m = sM[gg][le];
      const float Mn  = fmaxf(Mt, m);
      const float sc0 = __expf(Mt - Mn);
      const float sc1 = __expf(m - Mn);
      St = St * sc0 + sS[gg][le] * sc1;
      Ot = Ot * sc0 + sO[gg][le] * sc1;
      Mt = Mn;
    }
    out[(size_t)b * EE + e] = Ot / St;  // St > 0: c=0 always valid (lengths >= 1)
  }
}

extern "C" void kernel_launch(void* const* d_in, const int* in_sizes, int n_in,
                              void* d_out, int out_size, void* d_ws, size_t ws_size,
                              hipStream_t stream) {
  const float* enc  = (const float*)d_in[0];
  const int*   lens = (const int*)d_in[1];
  const float* Wh   = (const float*)d_in[2];
  const float* bh   = (const float*)d_in[3];
  const float* Wc   = (const float*)d_in[4];
  float* out = (float*)d_out;

  const size_t wbytes = (size_t)512 * 512 * sizeof(unsigned short);
  int C = 64;  // Lc=32 -> one 32-row pass per item (pairing fuses two per joint pass)
  while (C > 8 && ws_size < (size_t)3 * BB * C * EE * sizeof(float) + 2 * wbytes + 64)
    C >>= 1;
  const int Lc = LL / C;

  float* pm = (float*)d_ws;
  float* ps = pm + (size_t)BB * C * EE;
  float* po = ps + (size_t)BB * C * EE;
  unsigned short* WhT = (unsigned short*)(po + (size_t)BB * C * EE);
  unsigned short* WcT = WhT + (size_t)512 * 512;
  int* q = (int*)(WcT + (size_t)512 * 512);

  prep_w<<<dim3(64, 2), 256, 0, stream>>>(Wh, Wc, WhT, WcT, q);
  attn_main<<<dim3(512), 512, 0, stream>>>(enc, lens, WhT, bh, WcT, pm, ps, po, q, C, Lc);
  attn_combine<<<dim3(8, BB), 256, 0, stream>>>(pm, ps, po, lens, out, C, Lc);
}